// Round 1
// baseline (68.680 us; speedup 1.0000x reference)
//
#include <hip/hip_runtime.h>
#include <math.h>

// Problem constants (match reference setup)
#define NUM_EGO   32
#define AGENTS_PER 128
#define T_TOTAL   34
#define H_OFF     4
#define TN        30           // T_TOTAL - H
#define SCALE     1.9f         // LEAST_MIN_TTC / DT = 0.95 / 0.5

__global__ void ttc_init_out(float* __restrict__ out) {
    int i = threadIdx.x;
    if (i < NUM_EGO) out[i] = 1.0f;
}

// One block per (ego b, timestep t). 128 threads = one per agent in the block.
__global__ __launch_bounds__(AGENTS_PER) void ttc_main(
    const float* __restrict__ posg,     // (N, 34, 2)
    const float* __restrict__ headg,    // (N, 34)
    const float* __restrict__ boxg,     // (N, 4)
    const int*   __restrict__ validg,   // (N, 34) 0/1
    const int*   __restrict__ ptrg,     // (33,)
    float* __restrict__ out)            // (32,)
{
    const int blk = blockIdx.x;
    const int b   = blk / TN;          // ego index
    const int t   = blk % TN;          // relative time 0..29
    const int tt  = t + H_OFF;         // absolute time index

    __shared__ float s_ego[16];        // [0]=ex [1]=ey [2]=cos [3]=sin [4..11]=4 corners(x,y) [12..15]=box f,r,l,rt
    __shared__ int   s_evalid;
    __shared__ int   s_any;
    __shared__ int   s_e0, s_e1;

    if (threadIdx.x == 0) {
        int e0 = ptrg[b];
        int e1 = ptrg[b + 1];
        s_e0 = e0; s_e1 = e1;
        s_any = 0;
        const int e = e0;
        s_evalid = validg[e * T_TOTAL + tt];
        float px1 = posg[(e * T_TOTAL + tt) * 2 + 0];
        float py1 = posg[(e * T_TOTAL + tt) * 2 + 1];
        float px0 = posg[(e * T_TOTAL + tt - 1) * 2 + 0];
        float py0 = posg[(e * T_TOTAL + tt - 1) * 2 + 1];
        float ex = px1 + SCALE * (px1 - px0);
        float ey = py1 + SCALE * (py1 - py0);
        float yaw = headg[e * T_TOTAL + tt];
        float c = cosf(yaw), s = sinf(yaw);
        float f  = boxg[e * 4 + 0];
        float r  = boxg[e * 4 + 1];
        float l  = boxg[e * 4 + 2];
        float rt = boxg[e * 4 + 3];
        s_ego[0] = ex; s_ego[1] = ey; s_ego[2] = c; s_ego[3] = s;
        float lxs[4] = { f,  f, -r, -r };
        float lys[4] = { l, -rt, -rt,  l };
        #pragma unroll
        for (int k = 0; k < 4; ++k) {
            s_ego[4 + 2 * k] = lxs[k] * c - lys[k] * s + ex;
            s_ego[5 + 2 * k] = lxs[k] * s + lys[k] * c + ey;
        }
        s_ego[12] = f; s_ego[13] = r; s_ego[14] = l; s_ego[15] = rt;
    }
    __syncthreads();

    if (!s_evalid) return;   // uniform across block: row contributes nothing

    const int e0 = s_e0, e1 = s_e1;
    const int n = e0 + threadIdx.x;

    float loss = 0.0f;
    if (n < e1 && n != e0 && validg[n * T_TOTAL + tt] != 0) {
        // agent pose at absolute time tt with TTC extrapolation
        float px1 = posg[(n * T_TOTAL + tt) * 2 + 0];
        float py1 = posg[(n * T_TOTAL + tt) * 2 + 1];
        float px0 = posg[(n * T_TOTAL + tt - 1) * 2 + 0];
        float py0 = posg[(n * T_TOTAL + tt - 1) * 2 + 1];
        float ax = px1 + SCALE * (px1 - px0);
        float ay = py1 + SCALE * (py1 - py0);
        float ayaw = headg[n * T_TOTAL + tt];
        float ca = cosf(ayaw), sa = sinf(ayaw);
        float af  = boxg[n * 4 + 0];
        float ar  = boxg[n * 4 + 1];
        float al  = boxg[n * 4 + 2];
        float art = boxg[n * 4 + 3];

        const float ex = s_ego[0], ey = s_ego[1];
        const float ce = s_ego[2], se = s_ego[3];
        const float ef = s_ego[12], er = s_ego[13], el = s_ego[14], ert = s_ego[15];

        // L1: ego corners in agent frame, agent box
        float L1 = 0.0f;
        #pragma unroll
        for (int k = 0; k < 4; ++k) {
            float dx = s_ego[4 + 2 * k] - ax;
            float dy = s_ego[5 + 2 * k] - ay;
            float lx =  dx * ca + dy * sa;
            float ly = -dx * sa + dy * ca;
            float lo = fminf(fmaxf(af - lx, 0.0f), fmaxf(ar + lx, 0.0f));
            float la = fminf(fmaxf(al - ly, 0.0f), fmaxf(art + ly, 0.0f));
            L1 = fmaxf(L1, fminf(lo, la));
        }

        // L2: agent corners in ego frame, ego box
        float lxs[4] = { af,  af, -ar, -ar };
        float lys[4] = { al, -art, -art,  al };
        float L2 = 0.0f;
        #pragma unroll
        for (int k = 0; k < 4; ++k) {
            float cxw = lxs[k] * ca - lys[k] * sa + ax;
            float cyw = lxs[k] * sa + lys[k] * ca + ay;
            float dx = cxw - ex;
            float dy = cyw - ey;
            float lx =  dx * ce + dy * se;
            float ly = -dx * se + dy * ce;
            float lo = fminf(fmaxf(ef - lx, 0.0f), fmaxf(er + lx, 0.0f));
            float la = fminf(fmaxf(el - ly, 0.0f), fmaxf(ert + ly, 0.0f));
            L2 = fmaxf(L2, fminf(lo, la));
        }

        loss = fmaxf(L1, L2);
    }

    if (loss > 0.0f) s_any = 1;   // benign multi-writer of identical value
    __syncthreads();
    if (threadIdx.x == 0 && s_any) {
        out[b] = 0.0f;            // benign same-value race across t-blocks
    }
}

extern "C" void kernel_launch(void* const* d_in, const int* in_sizes, int n_in,
                              void* d_out, int out_size, void* d_ws, size_t ws_size,
                              hipStream_t stream) {
    const float* posg   = (const float*)d_in[0];  // infer_position (N,34,2)
    const float* headg  = (const float*)d_in[1];  // infer_heading  (N,34)
    const float* boxg   = (const float*)d_in[2];  // box            (N,4)
    const int*   validg = (const int*)  d_in[3];  // infer_valid_mask (N,34)
    // d_in[4] = batch (unused: implied by ptr blocks)
    const int*   ptrg   = (const int*)  d_in[5];  // ptr (33,)
    float* out = (float*)d_out;

    ttc_init_out<<<1, 64, 0, stream>>>(out);
    ttc_main<<<NUM_EGO * TN, AGENTS_PER, 0, stream>>>(posg, headg, boxg, validg, ptrg, out);
}